// Round 1
// baseline (309.523 us; speedup 1.0000x reference)
//
#include <hip/hip_runtime.h>
#include <hip/hip_bf16.h>

typedef __attribute__((ext_vector_type(4))) float f32x4;
typedef __attribute__((ext_vector_type(8))) short s16x8;
typedef __attribute__((ext_vector_type(4))) short s16x4;

#define DEV static __device__ __forceinline__

// fp32 -> bf16 round-to-nearest-even
DEV unsigned short f2bf(float f) {
    unsigned int u = __builtin_bit_cast(unsigned int, f);
    u += 0x7fffu + ((u >> 16) & 1u);
    return (unsigned short)(u >> 16);
}

// load 8 contiguous bf16 (as shorts) from LDS via two 8B reads (stride-68/36 keeps only 8B alignment)
DEV s16x8 ld8(const unsigned short* p) {
    s16x4 lo = *(const s16x4*)(p);
    s16x4 hi = *(const s16x4*)(p + 4);
    return __builtin_shufflevector(lo, hi, 0, 1, 2, 3, 4, 5, 6, 7);
}

DEV f32x4 mfma16(s16x8 a, s16x8 b, f32x4 c) {
    return __builtin_amdgcn_mfma_f32_16x16x32_bf16(a, b, c, 0, 0, 0);
}

// ---------------------------------------------------------------------------
// Kernel 1: QKV projection.  C[4096][3072] = X[4096][1024] * Wqkv[3072][1024]^T
// Epilogue scatters bf16 into q/k/v workspaces laid out [B*H][T][64].
// Block tile 64x64, BK=32, 4 waves (2x2), each wave 32x32 (2x2 MFMA tiles).
// ---------------------------------------------------------------------------
__global__ __launch_bounds__(256) void qkv_gemm(
        const float* __restrict__ X, const float* __restrict__ W,
        unsigned short* __restrict__ q_ws, unsigned short* __restrict__ k_ws,
        unsigned short* __restrict__ v_ws) {
    constexpr int LDA = 36;  // padded stride in shorts: 36*2B=72B, dword stride 18, gcd(18,32)=2 -> free
    __shared__ unsigned short As[64 * LDA];
    __shared__ unsigned short Bs[64 * LDA];
    const int tid  = threadIdx.x;
    const int lane = tid & 63;
    const int wave = tid >> 6;
    const int wm = (wave >> 1) * 32, wn = (wave & 1) * 32;
    const int l15 = lane & 15, l4 = lane >> 4;
    const int m0 = blockIdx.y * 64, n0 = blockIdx.x * 64;
    const int srow = tid >> 2, scol = (tid & 3) * 8;

    f32x4 acc[2][2];
    for (int i = 0; i < 2; i++)
        for (int j = 0; j < 2; j++) acc[i][j] = (f32x4){0.f, 0.f, 0.f, 0.f};

    for (int k0 = 0; k0 < 1024; k0 += 32) {
        float4 a0 = *(const float4*)&X[(size_t)(m0 + srow) * 1024 + k0 + scol];
        float4 a1 = *(const float4*)&X[(size_t)(m0 + srow) * 1024 + k0 + scol + 4];
        float4 b0 = *(const float4*)&W[(size_t)(n0 + srow) * 1024 + k0 + scol];
        float4 b1 = *(const float4*)&W[(size_t)(n0 + srow) * 1024 + k0 + scol + 4];
        __syncthreads();  // previous iteration's fragment reads complete
        s16x4 av0 = {(short)f2bf(a0.x), (short)f2bf(a0.y), (short)f2bf(a0.z), (short)f2bf(a0.w)};
        s16x4 av1 = {(short)f2bf(a1.x), (short)f2bf(a1.y), (short)f2bf(a1.z), (short)f2bf(a1.w)};
        s16x4 bv0 = {(short)f2bf(b0.x), (short)f2bf(b0.y), (short)f2bf(b0.z), (short)f2bf(b0.w)};
        s16x4 bv1 = {(short)f2bf(b1.x), (short)f2bf(b1.y), (short)f2bf(b1.z), (short)f2bf(b1.w)};
        *(s16x4*)&As[srow * LDA + scol]     = av0;
        *(s16x4*)&As[srow * LDA + scol + 4] = av1;
        *(s16x4*)&Bs[srow * LDA + scol]     = bv0;
        *(s16x4*)&Bs[srow * LDA + scol + 4] = bv1;
        __syncthreads();
        s16x8 af[2], bf[2];
        for (int mt = 0; mt < 2; mt++) af[mt] = ld8(&As[(wm + mt * 16 + l15) * LDA + l4 * 8]);
        for (int nt = 0; nt < 2; nt++) bf[nt] = ld8(&Bs[(wn + nt * 16 + l15) * LDA + l4 * 8]);
        for (int mt = 0; mt < 2; mt++)
            for (int nt = 0; nt < 2; nt++)
                acc[mt][nt] = mfma16(af[mt], bf[nt], acc[mt][nt]);
    }

    // Scatter epilogue: n0 is 64-aligned so the whole block lands in one (which, h).
    const int which = n0 >> 10;
    const int h     = (n0 & 1023) >> 6;
    const int bidx  = m0 >> 11;
    unsigned short* dst = (which == 0) ? q_ws : (which == 1) ? k_ws : v_ws;
    dst += (size_t)(bidx * 16 + h) * 2048 * 64;
    const int tb = m0 & 2047;
    for (int mt = 0; mt < 2; mt++)
        for (int nt = 0; nt < 2; nt++)
            for (int r = 0; r < 4; r++) {
                int t  = tb + wm + mt * 16 + l4 * 4 + r;   // C/D layout: row=(lane>>4)*4+reg
                int dh = wn + nt * 16 + l15;               //            col=lane&15
                dst[(size_t)t * 64 + dh] = f2bf(acc[mt][nt][r]);
            }
}

// ---------------------------------------------------------------------------
// Kernel 2: causal flash attention.  One block per (b*h, q-tile of 64 rows).
// q/k/v bf16 [B*H][2048][64].  Output attn_out bf16 [B][T][H*64].
// 4 waves; each wave owns 16 q-rows. Online softmax in fp32.
// ---------------------------------------------------------------------------
__global__ __launch_bounds__(256) void attn(
        const unsigned short* __restrict__ q_ws, const unsigned short* __restrict__ k_ws,
        const unsigned short* __restrict__ v_ws, unsigned short* __restrict__ attn_out) {
    constexpr int LDK = 68;  // 68*2B=136B, dword stride 34, gcd(34,32)=2 -> free 2-way
    __shared__ unsigned short Ks[64 * LDK];         // K tile, natural [key][d]
    __shared__ unsigned short Vt[64 * LDK];         // V tile transposed [d][key]
    __shared__ unsigned short Ps[4 * 16 * LDK];     // per-wave P (C-layout -> A-layout round trip)
    const int tid  = threadIdx.x;
    const int lane = tid & 63;
    const int wave = tid >> 6;
    const int l15 = lane & 15, l4 = lane >> 4;
    const int bh = blockIdx.y;
    const int b = bh >> 4, h = bh & 15;
    const int q0 = blockIdx.x * 64;
    const size_t base = (size_t)bh * 2048 * 64;
    const int srow = tid >> 2, scol = (tid & 3) * 16;

    // Q fragments straight from global (one-time, per wave rows wave*16..+16)
    const int qrow = q0 + wave * 16 + l15;
    s16x8 qf[2];
    qf[0] = *(const s16x8*)&q_ws[base + (size_t)qrow * 64 + l4 * 8];
    qf[1] = *(const s16x8*)&q_ws[base + (size_t)qrow * 64 + 32 + l4 * 8];

    f32x4 o[4];
    for (int i = 0; i < 4; i++) o[i] = (f32x4){0.f, 0.f, 0.f, 0.f};
    float mrow[4] = {-1e30f, -1e30f, -1e30f, -1e30f};
    float lrow[4] = {0.f, 0.f, 0.f, 0.f};

    unsigned short* Pw = &Ps[wave * 16 * LDK];
    const float scale = 0.125f;  // 64^-0.5

    for (int k0 = 0; k0 <= q0; k0 += 64) {
        // ---- stage K (natural) and V (transposed) ----
        s16x8 kv0 = *(const s16x8*)&k_ws[base + (size_t)(k0 + srow) * 64 + scol];
        s16x8 kv1 = *(const s16x8*)&k_ws[base + (size_t)(k0 + srow) * 64 + scol + 8];
        s16x8 vv0 = *(const s16x8*)&v_ws[base + (size_t)(k0 + srow) * 64 + scol];
        s16x8 vv1 = *(const s16x8*)&v_ws[base + (size_t)(k0 + srow) * 64 + scol + 8];
        __syncthreads();  // previous tile fully consumed
        *(s16x4*)&Ks[srow * LDK + scol]      = __builtin_shufflevector(kv0, kv0, 0, 1, 2, 3);
        *(s16x4*)&Ks[srow * LDK + scol + 4]  = __builtin_shufflevector(kv0, kv0, 4, 5, 6, 7);
        *(s16x4*)&Ks[srow * LDK + scol + 8]  = __builtin_shufflevector(kv1, kv1, 0, 1, 2, 3);
        *(s16x4*)&Ks[srow * LDK + scol + 12] = __builtin_shufflevector(kv1, kv1, 4, 5, 6, 7);
        for (int i = 0; i < 8; i++) {
            Vt[(scol + i) * LDK + srow]     = (unsigned short)vv0[i];
            Vt[(scol + 8 + i) * LDK + srow] = (unsigned short)vv1[i];
        }
        __syncthreads();

        // ---- S = Q K^T (per wave: 16 q-rows x 64 keys) ----
        f32x4 s[4];
        for (int i = 0; i < 4; i++) s[i] = (f32x4){0.f, 0.f, 0.f, 0.f};
        for (int sub = 0; sub < 4; sub++) {
            const unsigned short* kp = &Ks[(sub * 16 + l15) * LDK];
            s16x8 kf0 = ld8(kp + l4 * 8);
            s16x8 kf1 = ld8(kp + 32 + l4 * 8);
            s[sub] = mfma16(qf[0], kf0, s[sub]);
            s[sub] = mfma16(qf[1], kf1, s[sub]);
        }

        // ---- scale + causal mask + online softmax; P -> LDS (bf16) ----
        for (int r = 0; r < 4; r++) {
            int qg = q0 + wave * 16 + l4 * 4 + r;
            float mx = -1e30f;
            for (int sub = 0; sub < 4; sub++) {
                float v = s[sub][r] * scale;
                int kg = k0 + sub * 16 + l15;
                if (kg > qg) v = -1e30f;
                s[sub][r] = v;
                mx = fmaxf(mx, v);
            }
            for (int off = 1; off < 16; off <<= 1)
                mx = fmaxf(mx, __shfl_xor(mx, off, 16));
            float mn = fmaxf(mrow[r], mx);
            float alpha = __expf(mrow[r] - mn);
            mrow[r] = mn;
            float rs = 0.f;
            for (int sub = 0; sub < 4; sub++) {
                float p = __expf(s[sub][r] - mn);
                rs += p;
                Pw[(l4 * 4 + r) * LDK + sub * 16 + l15] = f2bf(p);
            }
            for (int off = 1; off < 16; off <<= 1)
                rs += __shfl_xor(rs, off, 16);
            lrow[r] = lrow[r] * alpha + rs;
            for (int dt = 0; dt < 4; dt++) o[dt][r] *= alpha;
        }
        __syncthreads();  // P visible (uniform barrier count across waves)

        // ---- O += P V ----
        s16x8 pf0 = ld8(&Pw[l15 * LDK + l4 * 8]);
        s16x8 pf1 = ld8(&Pw[l15 * LDK + 32 + l4 * 8]);
        for (int sub = 0; sub < 4; sub++) {
            const unsigned short* vp = &Vt[(sub * 16 + l15) * LDK];
            s16x8 vf0 = ld8(vp + l4 * 8);
            s16x8 vf1 = ld8(vp + 32 + l4 * 8);
            o[sub] = mfma16(pf0, vf0, o[sub]);
            o[sub] = mfma16(pf1, vf1, o[sub]);
        }
    }

    // ---- epilogue: normalize and write [B][T][H*64] bf16 ----
    for (int r = 0; r < 4; r++) {
        float inv = 1.f / lrow[r];
        int t = q0 + wave * 16 + l4 * 4 + r;
        size_t ob = ((size_t)b * 2048 + t) * 1024 + h * 64;
        for (int dt = 0; dt < 4; dt++)
            attn_out[ob + dt * 16 + l15] = f2bf(o[dt][r] * inv);
    }
}

// ---------------------------------------------------------------------------
// Kernel 3: output projection. OUT[4096][1024] = AO[4096][1024](bf16) * Wout[1024][1024]^T
// ---------------------------------------------------------------------------
__global__ __launch_bounds__(256) void out_gemm(
        const unsigned short* __restrict__ AO, const float* __restrict__ W,
        float* __restrict__ OUT) {
    constexpr int LDA = 36;
    __shared__ unsigned short As[64 * LDA];
    __shared__ unsigned short Bs[64 * LDA];
    const int tid  = threadIdx.x;
    const int lane = tid & 63;
    const int wave = tid >> 6;
    const int wm = (wave >> 1) * 32, wn = (wave & 1) * 32;
    const int l15 = lane & 15, l4 = lane >> 4;
    const int m0 = blockIdx.y * 64, n0 = blockIdx.x * 64;
    const int srow = tid >> 2, scol = (tid & 3) * 8;

    f32x4 acc[2][2];
    for (int i = 0; i < 2; i++)
        for (int j = 0; j < 2; j++) acc[i][j] = (f32x4){0.f, 0.f, 0.f, 0.f};

    for (int k0 = 0; k0 < 1024; k0 += 32) {
        s16x8 a = *(const s16x8*)&AO[(size_t)(m0 + srow) * 1024 + k0 + scol];
        float4 b0 = *(const float4*)&W[(size_t)(n0 + srow) * 1024 + k0 + scol];
        float4 b1 = *(const float4*)&W[(size_t)(n0 + srow) * 1024 + k0 + scol + 4];
        __syncthreads();
        s16x4 bv0 = {(short)f2bf(b0.x), (short)f2bf(b0.y), (short)f2bf(b0.z), (short)f2bf(b0.w)};
        s16x4 bv1 = {(short)f2bf(b1.x), (short)f2bf(b1.y), (short)f2bf(b1.z), (short)f2bf(b1.w)};
        *(s16x4*)&As[srow * LDA + scol]     = __builtin_shufflevector(a, a, 0, 1, 2, 3);
        *(s16x4*)&As[srow * LDA + scol + 4] = __builtin_shufflevector(a, a, 4, 5, 6, 7);
        *(s16x4*)&Bs[srow * LDA + scol]     = bv0;
        *(s16x4*)&Bs[srow * LDA + scol + 4] = bv1;
        __syncthreads();
        s16x8 af[2], bf[2];
        for (int mt = 0; mt < 2; mt++) af[mt] = ld8(&As[(wm + mt * 16 + l15) * LDA + l4 * 8]);
        for (int nt = 0; nt < 2; nt++) bf[nt] = ld8(&Bs[(wn + nt * 16 + l15) * LDA + l4 * 8]);
        for (int mt = 0; mt < 2; mt++)
            for (int nt = 0; nt < 2; nt++)
                acc[mt][nt] = mfma16(af[mt], bf[nt], acc[mt][nt]);
    }

    for (int mt = 0; mt < 2; mt++)
        for (int nt = 0; nt < 2; nt++)
            for (int r = 0; r < 4; r++) {
                int gm = m0 + wm + mt * 16 + l4 * 4 + r;
                int gn = n0 + wn + nt * 16 + l15;
                OUT[(size_t)gm * 1024 + gn] = acc[mt][nt][r];
            }
}

// ---------------------------------------------------------------------------
extern "C" void kernel_launch(void* const* d_in, const int* in_sizes, int n_in,
                              void* d_out, int out_size, void* d_ws, size_t ws_size,
                              hipStream_t stream) {
    (void)in_sizes; (void)n_in; (void)out_size; (void)ws_size;
    const float* x    = (const float*)d_in[0];   // [2,2048,1024]
    const float* Wqkv = (const float*)d_in[1];   // [3072,1024]
    const float* Wout = (const float*)d_in[2];   // [1024,1024]
    float* out = (float*)d_out;                  // [2,2048,1024] fp32

    // workspace: 4 x 8MB bf16 regions = 32 MB
    unsigned short* q_ws = (unsigned short*)d_ws;
    unsigned short* k_ws = q_ws + (size_t)4 * 1024 * 1024;
    unsigned short* v_ws = k_ws + (size_t)4 * 1024 * 1024;
    unsigned short* ao   = v_ws + (size_t)4 * 1024 * 1024;

    qkv_gemm<<<dim3(48, 64), 256, 0, stream>>>(x, Wqkv, q_ws, k_ws, v_ws);
    attn<<<dim3(32, 32), 256, 0, stream>>>(q_ws, k_ws, v_ws, ao);
    out_gemm<<<dim3(16, 64), 256, 0, stream>>>(ao, Wout, out);
}

// Round 2
// 220.802 us; speedup vs baseline: 1.4018x; 1.4018x over previous
//
#include <hip/hip_runtime.h>
#include <hip/hip_bf16.h>

typedef __attribute__((ext_vector_type(4))) float f32x4;
typedef __attribute__((ext_vector_type(8))) short s16x8;
typedef __attribute__((ext_vector_type(4))) short s16x4;

#define DEV static __device__ __forceinline__

// fp32 -> bf16 round-to-nearest-even
DEV unsigned short f2bf(float f) {
    unsigned int u = __builtin_bit_cast(unsigned int, f);
    u += 0x7fffu + ((u >> 16) & 1u);
    return (unsigned short)(u >> 16);
}

// 8 bf16 from LDS via two 8B reads (for padded strides: only 8B alignment)
DEV s16x8 ld8(const unsigned short* p) {
    s16x4 lo = *(const s16x4*)(p);
    s16x4 hi = *(const s16x4*)(p + 4);
    return __builtin_shufflevector(lo, hi, 0, 1, 2, 3, 4, 5, 6, 7);
}
// 16B-aligned single b128 read (unpadded 64B-row layouts)
DEV s16x8 ld8a(const unsigned short* p) { return *(const s16x8*)p; }

DEV f32x4 mfma16(s16x8 a, s16x8 b, f32x4 c) {
    return __builtin_amdgcn_mfma_f32_16x16x32_bf16(a, b, c, 0, 0, 0);
}

// async global->LDS, 16B per lane; lds ptr must be wave-uniform (dest = base + lane*16)
DEV void glds16(const unsigned short* g, unsigned short* l) {
    __builtin_amdgcn_global_load_lds(
        (const __attribute__((address_space(1))) unsigned int*)g,
        (__attribute__((address_space(3))) unsigned int*)l, 16, 0, 0);
}

// ---------------------------------------------------------------------------
// fp32 -> bf16 bulk cast (memory-bound, ~1-3 us each)
// ---------------------------------------------------------------------------
__global__ __launch_bounds__(256) void convf2b(const float* __restrict__ s,
                                               unsigned short* __restrict__ d, int n4) {
    int i = blockIdx.x * 256 + threadIdx.x;
    if (i < n4) {
        float4 v = ((const float4*)s)[i];
        s16x4 o = {(short)f2bf(v.x), (short)f2bf(v.y), (short)f2bf(v.z), (short)f2bf(v.w)};
        ((s16x4*)d)[i] = o;
    }
}

// ---------------------------------------------------------------------------
// QKV projection: C[4096][3072] = X[4096][1024](fp32) * Wq[3072][1024](bf16)^T
// m97 structure: 128x128 tile, BK=32, 4 waves each 64x64 (acc[4][4]).
// A staged via VGPR fp32->bf16 convert (padded LDS); B via global_load_lds.
// Epilogue scatters bf16 into q/k/v [B*H][T][64]; q pre-scaled by Dh^-0.5.
// ---------------------------------------------------------------------------
__global__ __launch_bounds__(256) void qkv_gemm(
        const float* __restrict__ X, const unsigned short* __restrict__ Wq,
        unsigned short* __restrict__ q_ws, unsigned short* __restrict__ k_ws,
        unsigned short* __restrict__ v_ws) {
    constexpr int LDA = 36;  // dword stride 18, gcd(18,32)=2 -> free 2-way
    __shared__ unsigned short As[128 * LDA];
    __shared__ unsigned short Bs[128 * 32];  // unpadded: global_load_lds layout
    const int tid = threadIdx.x, lane = tid & 63, wave = tid >> 6;
    const int l15 = lane & 15, l4 = lane >> 4;
    const int wm = (wave >> 1) * 64, wn = (wave & 1) * 64;
    const int m0 = blockIdx.y * 128, n0 = blockIdx.x * 128;
    const int arow = tid >> 1, acol = (tid & 1) * 16;

    f32x4 acc[4][4];
    for (int i = 0; i < 4; i++)
        for (int j = 0; j < 4; j++) acc[i][j] = (f32x4){0.f, 0.f, 0.f, 0.f};

    const float* aptr = &X[(size_t)(m0 + arow) * 1024 + acol];
    const unsigned short* bptr = &Wq[(size_t)(n0 + wave * 32 + (lane >> 2)) * 1024 + (lane & 3) * 8];
    unsigned short* bs0 = &Bs[(wave * 32) * 32];
    unsigned short* bs1 = &Bs[(wave * 32 + 16) * 32];

    for (int k0 = 0; k0 < 1024; k0 += 32) {
        float4 a[4];
        for (int i = 0; i < 4; i++) a[i] = *(const float4*)(aptr + k0 + 4 * i);
        __syncthreads();  // previous iter's fragment reads done
        glds16(bptr + k0, bs0);
        glds16(bptr + k0 + 16 * 1024, bs1);
        for (int i = 0; i < 4; i++) {
            s16x4 p = {(short)f2bf(a[i].x), (short)f2bf(a[i].y),
                       (short)f2bf(a[i].z), (short)f2bf(a[i].w)};
            *(s16x4*)&As[arow * LDA + acol + 4 * i] = p;
        }
        __syncthreads();  // staging visible (vmcnt+lgkmcnt drained by compiler)
        s16x8 af[4], bf[4];
        for (int mt = 0; mt < 4; mt++) af[mt] = ld8(&As[(wm + mt * 16 + l15) * LDA + l4 * 8]);
        for (int nt = 0; nt < 4; nt++) bf[nt] = ld8a(&Bs[(wn + nt * 16 + l15) * 32 + l4 * 8]);
        for (int mt = 0; mt < 4; mt++)
            for (int nt = 0; nt < 4; nt++)
                acc[mt][nt] = mfma16(af[mt], bf[nt], acc[mt][nt]);
    }

    // scatter epilogue (C/D layout: row=(lane>>4)*4+reg, col=lane&15)
    for (int mt = 0; mt < 4; mt++) {
        int mbase = m0 + wm + mt * 16 + l4 * 4;
        for (int nt = 0; nt < 4; nt++) {
            int gn = n0 + wn + nt * 16 + l15;
            int which = gn >> 10, h = (gn >> 6) & 15, dh = gn & 63;
            unsigned short* dst = (which == 0) ? q_ws : (which == 1) ? k_ws : v_ws;
            float sc = (which == 0) ? 0.125f : 1.0f;  // fold Dh^-0.5 into q
            for (int r = 0; r < 4; r++) {
                int mm = mbase + r;
                dst[((size_t)((mm >> 11) * 16 + h) * 2048 + (mm & 2047)) * 64 + dh] =
                    f2bf(acc[mt][nt][r] * sc);
            }
        }
    }
}

// ---------------------------------------------------------------------------
// Causal flash attention v2.  Block = (bh, 128 q-rows), 4 waves x 32 q-rows.
// S^T = K*Q^T so softmax reduces over l4 (2 shuffles); O accumulated as O^T
// so alpha/1-l are per-lane multiplies. P round-trips LDS in packed b64.
// ---------------------------------------------------------------------------
__global__ __launch_bounds__(256) void attn(
        const unsigned short* __restrict__ q_ws, const unsigned short* __restrict__ k_ws,
        const unsigned short* __restrict__ v_ws, unsigned short* __restrict__ ao) {
    constexpr int LDK = 68, LDV = 68, LDP = 68;
    __shared__ unsigned short Ks[64 * LDK];      // [key][d]
    __shared__ unsigned short Vt[64 * LDV];      // [d][key]
    __shared__ unsigned short Ps[4 * 32 * LDP];  // per-wave P [q][key] (reused for O in epilogue)
    const int tid = threadIdx.x, lane = tid & 63, wave = tid >> 6;
    const int l15 = lane & 15, l4 = lane >> 4;
    const int bh = blockIdx.x, b = bh >> 4, h = bh & 15;
    const int q0 = (15 - blockIdx.y) * 128;  // reversed: heaviest q-tiles dispatch first
    const int qw0 = q0 + wave * 32;
    const size_t base = (size_t)bh * 2048 * 64;
    const int srow = tid >> 2, scol = (tid & 3) * 16;
    unsigned short* Pw = &Ps[wave * 32 * LDP];

    // Q fragments (B-operand: rows=q, cols=d), register-resident; q pre-scaled.
    s16x8 qf[2][2];
    for (int qs = 0; qs < 2; qs++)
        for (int c = 0; c < 2; c++)
            qf[qs][c] = *(const s16x8*)&q_ws[base + (size_t)(qw0 + qs * 16 + l15) * 64 + c * 32 + l4 * 8];

    f32x4 o[4][2];  // O^T tiles [dsub][qsub]: row=d, col=q
    for (int i = 0; i < 4; i++)
        for (int j = 0; j < 2; j++) o[i][j] = (f32x4){0.f, 0.f, 0.f, 0.f};
    float m[2] = {-1e30f, -1e30f}, l[2] = {0.f, 0.f};

    const int kend = q0 + 128;
    for (int k0 = 0; k0 < kend; k0 += 64) {
        s16x8 ka = *(const s16x8*)&k_ws[base + (size_t)(k0 + srow) * 64 + scol];
        s16x8 kb = *(const s16x8*)&k_ws[base + (size_t)(k0 + srow) * 64 + scol + 8];
        s16x8 va = *(const s16x8*)&v_ws[base + (size_t)(k0 + srow) * 64 + scol];
        s16x8 vb = *(const s16x8*)&v_ws[base + (size_t)(k0 + srow) * 64 + scol + 8];
        __syncthreads();  // all waves done reading previous Ks/Vt
        *(s16x4*)&Ks[srow * LDK + scol]      = __builtin_shufflevector(ka, ka, 0, 1, 2, 3);
        *(s16x4*)&Ks[srow * LDK + scol + 4]  = __builtin_shufflevector(ka, ka, 4, 5, 6, 7);
        *(s16x4*)&Ks[srow * LDK + scol + 8]  = __builtin_shufflevector(kb, kb, 0, 1, 2, 3);
        *(s16x4*)&Ks[srow * LDK + scol + 12] = __builtin_shufflevector(kb, kb, 4, 5, 6, 7);
        for (int i = 0; i < 8; i++) {
            Vt[(scol + i) * LDV + srow]     = (unsigned short)va[i];
            Vt[(scol + 8 + i) * LDV + srow] = (unsigned short)vb[i];
        }
        __syncthreads();

        if (k0 < qw0 + 32) {  // wave-uniform: this wave needs the tile
            // S^T tiles [ksub][qsub]: row=key, col=q
            f32x4 st[4][2];
            for (int ks = 0; ks < 4; ks++)
                for (int qs = 0; qs < 2; qs++) st[ks][qs] = (f32x4){0.f, 0.f, 0.f, 0.f};
            for (int c = 0; c < 2; c++)
                for (int ks = 0; ks < 4; ks++) {
                    s16x8 kf = ld8(&Ks[(ks * 16 + l15) * LDK + c * 32 + l4 * 8]);
                    st[ks][0] = mfma16(kf, qf[0][c], st[ks][0]);
                    st[ks][1] = mfma16(kf, qf[1][c], st[ks][1]);
                }

            for (int qs = 0; qs < 2; qs++) {
                if (k0 + 63 > qw0 + qs * 16) {  // diagonal region only (wave-uniform)
                    int qg = qw0 + qs * 16 + l15;
                    for (int ks = 0; ks < 4; ks++)
                        for (int r = 0; r < 4; r++) {
                            int kg = k0 + ks * 16 + l4 * 4 + r;
                            if (kg > qg) st[ks][qs][r] = -1e30f;
                        }
                }
                // in-register max over 16 keys, then 2 cross-l4 shuffles
                f32x4 mv = st[0][qs];
                for (int ks = 1; ks < 4; ks++)
                    for (int r = 0; r < 4; r++) mv[r] = fmaxf(mv[r], st[ks][qs][r]);
                float mx = fmaxf(fmaxf(mv[0], mv[1]), fmaxf(mv[2], mv[3]));
                mx = fmaxf(mx, __shfl_xor(mx, 16, 64));
                mx = fmaxf(mx, __shfl_xor(mx, 32, 64));
                float mnew = fmaxf(m[qs], mx);
                float alpha = __expf(m[qs] - mnew);
                m[qs] = mnew;
                float rs = 0.f;
                for (int ks = 0; ks < 4; ks++) {
                    s16x4 pp;
                    for (int r = 0; r < 4; r++) {
                        float p = __expf(st[ks][qs][r] - mnew);
                        rs += p;
                        pp[r] = (short)f2bf(p);
                    }
                    *(s16x4*)&Pw[(qs * 16 + l15) * LDP + ks * 16 + l4 * 4] = pp;  // P[q][key]
                }
                rs += __shfl_xor(rs, 16, 64);
                rs += __shfl_xor(rs, 32, 64);
                l[qs] = l[qs] * alpha + rs;
                for (int ds = 0; ds < 4; ds++) o[ds][qs] *= alpha;  // alpha per l15=q: direct
            }

            // O^T += V^T * P^T : mfma(a=V^T rows=d, b=P rows=q)
            s16x8 pf[2][2];
            for (int qs = 0; qs < 2; qs++)
                for (int c = 0; c < 2; c++)
                    pf[qs][c] = ld8(&Pw[(qs * 16 + l15) * LDP + c * 32 + l4 * 8]);
            for (int ds = 0; ds < 4; ds++)
                for (int c = 0; c < 2; c++) {
                    s16x8 vf = ld8(&Vt[(ds * 16 + l15) * LDV + c * 32 + l4 * 8]);
                    o[ds][0] = mfma16(vf, pf[0][c], o[ds][0]);
                    o[ds][1] = mfma16(vf, pf[1][c], o[ds][1]);
                }
        }
    }

    // epilogue: normalize, transpose via per-wave LDS region, coalesced store
    float inv[2] = {1.f / l[0], 1.f / l[1]};
    for (int ds = 0; ds < 4; ds++)
        for (int qs = 0; qs < 2; qs++) {
            s16x4 pp;
            for (int r = 0; r < 4; r++) pp[r] = (short)f2bf(o[ds][qs][r] * inv[qs]);
            *(s16x4*)&Pw[(qs * 16 + l15) * LDP + ds * 16 + l4 * 4] = pp;  // Ow[q][d]
        }
    int qr = lane >> 1, half = lane & 1;
    size_t orow = ((size_t)b * 2048 + q0 + wave * 32 + qr) * 1024 + h * 64 + half * 32;
    for (int j = 0; j < 4; j++) {
        s16x8 vv = ld8(&Pw[qr * LDP + half * 32 + j * 8]);
        *(s16x8*)&ao[orow + j * 8] = vv;
    }
}

// ---------------------------------------------------------------------------
// Output projection: OUT[4096][1024](fp32) = AO[4096][1024](bf16) * Wo[1024][1024](bf16)^T
// Full m97 structure: both operands via global_load_lds, unpadded LDS.
// ---------------------------------------------------------------------------
__global__ __launch_bounds__(256) void out_gemm(
        const unsigned short* __restrict__ A, const unsigned short* __restrict__ Bm,
        float* __restrict__ OUT) {
    __shared__ unsigned short As[128 * 32];
    __shared__ unsigned short Bs[128 * 32];
    const int tid = threadIdx.x, lane = tid & 63, wave = tid >> 6;
    const int l15 = lane & 15, l4 = lane >> 4;
    const int wm = (wave >> 1) * 64, wn = (wave & 1) * 64;
    const int m0 = blockIdx.y * 128, n0 = blockIdx.x * 128;

    f32x4 acc[4][4];
    for (int i = 0; i < 4; i++)
        for (int j = 0; j < 4; j++) acc[i][j] = (f32x4){0.f, 0.f, 0.f, 0.f};

    const unsigned short* aptr = &A[(size_t)(m0 + wave * 32 + (lane >> 2)) * 1024 + (lane & 3) * 8];
    const unsigned short* bptr = &Bm[(size_t)(n0 + wave * 32 + (lane >> 2)) * 1024 + (lane & 3) * 8];
    unsigned short* as0 = &As[(wave * 32) * 32];
    unsigned short* as1 = &As[(wave * 32 + 16) * 32];
    unsigned short* bs0 = &Bs[(wave * 32) * 32];
    unsigned short* bs1 = &Bs[(wave * 32 + 16) * 32];

    for (int k0 = 0; k0 < 1024; k0 += 32) {
        __syncthreads();
        glds16(aptr + k0, as0);
        glds16(aptr + k0 + 16 * 1024, as1);
        glds16(bptr + k0, bs0);
        glds16(bptr + k0 + 16 * 1024, bs1);
        __syncthreads();
        s16x8 af[4], bf[4];
        for (int mt = 0; mt < 4; mt++) af[mt] = ld8a(&As[(wm + mt * 16 + l15) * 32 + l4 * 8]);
        for (int nt = 0; nt < 4; nt++) bf[nt] = ld8a(&Bs[(wn + nt * 16 + l15) * 32 + l4 * 8]);
        for (int mt = 0; mt < 4; mt++)
            for (int nt = 0; nt < 4; nt++)
                acc[mt][nt] = mfma16(af[mt], bf[nt], acc[mt][nt]);
    }

    for (int mt = 0; mt < 4; mt++)
        for (int nt = 0; nt < 4; nt++)
            for (int r = 0; r < 4; r++) {
                int gm = m0 + wm + mt * 16 + l4 * 4 + r;
                int gn = n0 + wn + nt * 16 + l15;
                OUT[(size_t)gm * 1024 + gn] = acc[mt][nt][r];
            }
}

// ---------------------------------------------------------------------------
extern "C" void kernel_launch(void* const* d_in, const int* in_sizes, int n_in,
                              void* d_out, int out_size, void* d_ws, size_t ws_size,
                              hipStream_t stream) {
    (void)in_sizes; (void)n_in; (void)out_size; (void)ws_size;
    const float* x    = (const float*)d_in[0];   // [2,2048,1024]
    const float* Wqkv = (const float*)d_in[1];   // [3072,1024]
    const float* Wout = (const float*)d_in[2];   // [1024,1024]
    float* out = (float*)d_out;                  // [2,2048,1024] fp32

    // 32 MB workspace, aliased:
    //   [0,8M)   q_ws bf16 [32][2048][64]; later reused for Wout-bf16 (out_gemm B)
    //   [8,16M)  k_ws
    //   [16,24M) v_ws
    //   [24,32M) Wqkv-bf16 (qkv_gemm B), then overwritten by attn output AO
    unsigned short* q_ws = (unsigned short*)d_ws;
    unsigned short* k_ws = q_ws + (size_t)4 * 1024 * 1024;
    unsigned short* v_ws = k_ws + (size_t)4 * 1024 * 1024;
    unsigned short* ao   = v_ws + (size_t)4 * 1024 * 1024;
    unsigned short* wqb  = ao;    // 6 MB, dead once qkv_gemm completes
    unsigned short* wob  = q_ws;  // 2 MB, written after attn completes

    convf2b<<<3072, 256, 0, stream>>>(Wqkv, wqb, 3072 * 1024 / 4);
    qkv_gemm<<<dim3(24, 32), 256, 0, stream>>>(x, wqb, q_ws, k_ws, v_ws);
    attn<<<dim3(32, 16), 256, 0, stream>>>(q_ws, k_ws, v_ws, ao);
    convf2b<<<1024, 256, 0, stream>>>(Wout, wob, 1024 * 1024 / 4);
    out_gemm<<<dim3(8, 32), 256, 0, stream>>>(ao, wob, out);
}